// Round 1
// baseline (191.475 us; speedup 1.0000x reference)
//
#include <hip/hip_runtime.h>
#include <math.h>

// PointLoss: fused masked reduction over B*H*W pixels -> scalar.
// Two kernels: main reduction writes per-block partials to d_ws,
// finalize reduces partials in double and writes d_out[0].

namespace {
constexpr int B_ = 64, H_ = 52, W_ = 720;
constexpr int HW_ = H_ * W_;           // 37440
constexpr int NPIX = B_ * HW_;         // 2396160
constexpr int NBLOCKS = 2048;          // 8 blocks/CU on 256 CUs
constexpr int NTHREADS = 256;
constexpr float EPSF = 1e-8f;
constexpr float RAD2DEG = 57.29577951308232f;  // 180/pi
}

__global__ __launch_bounds__(NTHREADS) void pointloss_main(
    const float* __restrict__ v,      // vertexmap_proj   [B,H,W,3]
    const float* __restrict__ nrm,    // normalmap_proj   [B,H,W,3]
    const float* __restrict__ unc,    // uncertainty      [B,H,W]
    const float* __restrict__ nown,   // now_normalmap    [B,H,W,3]
    const float* __restrict__ conf,   // now_confidencemap[B,H,W]
    const float* __restrict__ lastn,  // last_normalmap   [B,H,W,3]
    const float* __restrict__ lastv,  // last_vertexmap   [B,H,W,3]
    const int*   __restrict__ nowm,   // now_maskmap      [B,H,W]
    const int*   __restrict__ lastm,  // last_maskmap     [B,H,W]
    float* __restrict__ partials)     // [NBLOCKS*5]
{
    float s_m0 = 0.f, s_fov = 0.f, s_m = 0.f, s_icp = 0.f, s_ang = 0.f;
    const int stride = NBLOCKS * NTHREADS;
    for (int p = blockIdx.x * NTHREADS + threadIdx.x; p < NPIX; p += stride) {
        const float vx = v[3*p+0], vy = v[3*p+1], vz = v[3*p+2];
        const float ax = nown[3*p+0], ay = nown[3*p+1], az = nown[3*p+2];
        const bool mask0 = (nowm[p] > 0) &&
                           ((fabsf(ax) + fabsf(ay) + fabsf(az)) != 0.0f);

        const float depth = sqrtf(vx*vx + vy*vy + vz*vz + EPSF);
        const float yaw   = atan2f(vy, vx) * RAD2DEG;
        const float pitch = asinf(fminf(fmaxf(vz / depth, -1.f), 1.f)) * RAD2DEG;
        const float px = (180.0f - yaw) * 2.0f;   // /DH with DH=0.5
        const float py = (3.0f - pitch) * 2.0f;   // /DV with DV=0.5

        if (mask0) {
            const float dx = px - fminf(fmaxf(px, 0.f), (float)(W_ - 1));
            const float dy = py - fminf(fmaxf(py, 0.f), (float)(H_ - 1));
            s_m0 += 1.0f;
            s_fov += dx*dx + dy*dy;
        }

        // jnp.round = round-half-even -> rintf (v_rndne_f32)
        const float prx = rintf(px), pry = rintf(py);
        const bool inb = (prx >= 0.f) && (prx < (float)W_) &&
                         (pry >= 0.f) && (pry < (float)H_);

        if (mask0 && inb && (conf[p] >= 0.5f)) {
            // inb => no clamp needed for the gather index
            const int gi = (p / HW_) * HW_ + (int)pry * W_ + (int)prx;
            const float lx = lastn[3*gi+0], ly = lastn[3*gi+1], lz = lastn[3*gi+2];
            if ((lastm[gi] > 0) && ((fabsf(lx) + fabsf(ly) + fabsf(lz)) != 0.f)) {
                const float u  = unc[p];
                const float wx = lastv[3*gi+0], wy = lastv[3*gi+1], wz = lastv[3*gi+2];
                const float r  = lx*(vx-wx) + ly*(vy-wy) + lz*(vz-wz);
                const float nx = nrm[3*p+0], ny = nrm[3*p+1], nz = nrm[3*p+2];
                const float dt = lx*nx + ly*ny + lz*nz;
                const float den = (lx*lx + ly*ly + lz*lz) *
                                  (nx*nx + ny*ny + nz*nz) + EPSF;
                const float cosang = fabsf(dt) * rsqrtf(den);
                s_m   += 1.0f;
                s_icp += u * fabsf(r);
                s_ang += u * (1.0f - cosang);
            }
        }
    }

    // wave64 shuffle reduce
    #pragma unroll
    for (int off = 32; off > 0; off >>= 1) {
        s_m0  += __shfl_down(s_m0,  off);
        s_fov += __shfl_down(s_fov, off);
        s_m   += __shfl_down(s_m,   off);
        s_icp += __shfl_down(s_icp, off);
        s_ang += __shfl_down(s_ang, off);
    }
    __shared__ float red[NTHREADS / 64][5];
    const int lane = threadIdx.x & 63;
    const int wv   = threadIdx.x >> 6;
    if (lane == 0) {
        red[wv][0] = s_m0;  red[wv][1] = s_fov; red[wv][2] = s_m;
        red[wv][3] = s_icp; red[wv][4] = s_ang;
    }
    __syncthreads();
    if (threadIdx.x == 0) {
        float t[5] = {0.f, 0.f, 0.f, 0.f, 0.f};
        for (int w2 = 0; w2 < NTHREADS / 64; ++w2)
            for (int c = 0; c < 5; ++c) t[c] += red[w2][c];
        float* o = partials + blockIdx.x * 5;
        for (int c = 0; c < 5; ++c) o[c] = t[c];
    }
}

__global__ __launch_bounds__(256) void pointloss_finalize(
    const float* __restrict__ partials,
    const float* __restrict__ sx,
    const float* __restrict__ sq,
    float* __restrict__ out)
{
    double a0 = 0, a1 = 0, a2 = 0, a3 = 0, a4 = 0;
    for (int i = threadIdx.x; i < NBLOCKS; i += 256) {
        const float* pp = partials + i * 5;
        a0 += (double)pp[0]; a1 += (double)pp[1]; a2 += (double)pp[2];
        a3 += (double)pp[3]; a4 += (double)pp[4];
    }
    #pragma unroll
    for (int off = 32; off > 0; off >>= 1) {
        a0 += __shfl_down(a0, off);
        a1 += __shfl_down(a1, off);
        a2 += __shfl_down(a2, off);
        a3 += __shfl_down(a3, off);
        a4 += __shfl_down(a4, off);
    }
    __shared__ double red[4][5];
    const int lane = threadIdx.x & 63;
    const int wv   = threadIdx.x >> 6;
    if (lane == 0) {
        red[wv][0] = a0; red[wv][1] = a1; red[wv][2] = a2;
        red[wv][3] = a3; red[wv][4] = a4;
    }
    __syncthreads();
    if (threadIdx.x == 0) {
        double t[5] = {0, 0, 0, 0, 0};
        for (int w2 = 0; w2 < 4; ++w2)
            for (int c = 0; c < 5; ++c) t[c] += red[w2][c];
        const double n0 = fmax(t[0], 1.0);
        const double n  = fmax(t[2], 1.0);
        const double sx0 = (double)sx[0], sq0 = (double)sq[0];
        const double total = exp(-sx0) * (t[3] / n) + sx0
                           + exp(-sq0) * (t[4] / n) + sq0
                           + t[1] / n0;   // LAMDA = 1, ANGRATE = 1
        out[0] = (float)total;
    }
}

extern "C" void kernel_launch(void* const* d_in, const int* in_sizes, int n_in,
                              void* d_out, int out_size, void* d_ws, size_t ws_size,
                              hipStream_t stream) {
    const float* v     = (const float*)d_in[0];
    const float* nrm   = (const float*)d_in[1];
    const float* unc   = (const float*)d_in[2];
    const float* nown  = (const float*)d_in[3];
    const float* conf  = (const float*)d_in[4];
    const float* lastn = (const float*)d_in[5];
    const float* lastv = (const float*)d_in[6];
    const float* sx    = (const float*)d_in[7];
    const float* sq    = (const float*)d_in[8];
    const int*   nowm  = (const int*)d_in[9];
    const int*   lastm = (const int*)d_in[10];

    float* partials = (float*)d_ws;  // NBLOCKS*5 floats = 40 KB

    pointloss_main<<<NBLOCKS, NTHREADS, 0, stream>>>(
        v, nrm, unc, nown, conf, lastn, lastv, nowm, lastm, partials);
    pointloss_finalize<<<1, 256, 0, stream>>>(partials, sx, sq, (float*)d_out);
}